// Round 5
// baseline (788.988 us; speedup 1.0000x reference)
//
#include <hip/hip_runtime.h>
#include <hip/hip_bf16.h>

#define Bq 16
#define Cc 256
#define Ss 1024
#define Ll 64
#define Hh 8
#define DHd 64
#define INN 512
#define Pp 8
// SCALE * log2(e) folded into q so scores are in log2 domain
#define KSC 0.18033688011111772f

// per-i slot sizes (elements)
#define QSLOT    262144
#define MDSLOT   131072
#define HEATSLOT 1048576
#define OUTSLOT  8388608
#define KSLOT    8388608
#define WSLOT    393216
#define HALFO    4194304

typedef short s16x8 __attribute__((ext_vector_type(8)));
typedef float f32x4 __attribute__((ext_vector_type(4)));
typedef unsigned u32x2 __attribute__((ext_vector_type(2)));
typedef unsigned u32x4 __attribute__((ext_vector_type(4)));

__device__ __forceinline__ unsigned short f2bf(float f) {
    unsigned u = __builtin_bit_cast(unsigned, f);
    u += 0x7FFF + ((u >> 16) & 1);
    return (unsigned short)(u >> 16);
}
__device__ __forceinline__ float bf2f(unsigned short h) {
    return __builtin_bit_cast(float, (unsigned)h << 16);
}
__device__ __forceinline__ unsigned cvt_pk_bf16(float a, float b) {
    unsigned r;
    asm volatile("v_cvt_pk_bf16_f32 %0, %1, %2" : "=v"(r) : "v"(a), "v"(b));
    return r;
}
__device__ __forceinline__ u32x2 ds_tr16(const unsigned short* p) {
    u32x2 d;
    asm volatile("ds_read_b64_tr_b16 %0, %1"
                 : "=v"(d)
                 : "v"((const __attribute__((address_space(3))) unsigned short*)p)
                 : "memory");
    return d;
}

// ---------- W transpose + bf16 hi/lo split ----------------------------------
__global__ __launch_bounds__(256) void wsplit_kernel(
        const float* __restrict__ Wk, const float* __restrict__ Wv,
        unsigned short* __restrict__ Wth, unsigned short* __restrict__ Wtl,
        unsigned short* __restrict__ Wvh) {
    __shared__ float tile[64][65];
    int blk = blockIdx.x;              // 192 = i*64 + mat*32 + ns*4 + cb
    int i = blk >> 6, rem = blk & 63, mat = rem >> 5, ns = (rem >> 2) & 7, cb = rem & 3;
    int n0 = ns * 64, c0 = cb * 64, t = threadIdx.x;
    const float* W = (mat == 0 ? Wk : Wv) + (size_t)i * Cc * INN;
#pragma unroll
    for (int it = 0; it < 16; ++it) {
        int idx = t + it * 256; int cc = idx >> 6, nn = idx & 63;
        tile[cc][nn] = W[(size_t)(c0 + cc) * INN + n0 + nn];
    }
    __syncthreads();
#pragma unroll
    for (int it = 0; it < 16; ++it) {
        int idx = t + it * 256; int nn = idx >> 6, cc = idx & 63;
        float v = tile[cc][nn];
        unsigned short hi = f2bf(v);
        size_t o = (size_t)i * 131072 + (size_t)(n0 + nn) * Cc + c0 + cc;
        if (mat == 0) { Wth[o] = hi; Wtl[o] = f2bf(v - bf2f(hi)); }
        else          { Wvh[o] = hi; }
    }
}

// ---------- q = pp @ Wq[i] : f32, 4 l-rows per block for W reuse -------------
__global__ __launch_bounds__(256) void qk_kernel(const float* __restrict__ prot,
                                                 const float* __restrict__ Wq,
                                                 float* __restrict__ qout) {
    __shared__ float pcol[4][256];
    int blk = blockIdx.x;              // 384 = i*128 + p*16 + l4
    int i = blk >> 7, rem = blk & 127, p = rem >> 4, l4 = rem & 15;
    int t = threadIdx.x;
    const float* W = Wq + (size_t)i * Cc * INN;
#pragma unroll
    for (int it = 0; it < 4; ++it) {
        int idx = t + it * 256; int ll = idx >> 8, cc = idx & 255;
        pcol[ll][cc] = prot[((size_t)(i * Pp + p) * Cc + cc) * Ll + l4 * 4 + ll];
    }
    __syncthreads();
    float a0[4] = {0, 0, 0, 0}, a1[4] = {0, 0, 0, 0};
#pragma unroll 4
    for (int c = 0; c < Cc; ++c) {
        float w0 = W[c * INN + t], w1 = W[c * INN + t + 256];
#pragma unroll
        for (int ll = 0; ll < 4; ++ll) {
            a0[ll] += pcol[ll][c] * w0;
            a1[ll] += pcol[ll][c] * w1;
        }
    }
#pragma unroll
    for (int ll = 0; ll < 4; ++ll) {
        float* qo = qout + (size_t)i * QSLOT + (size_t)(p * 64 + l4 * 4 + ll) * INN;
        qo[t] = a0[ll]; qo[t + 256] = a1[ll];
    }
}

// ---------- K,V projection: x LDS-staged, wave-per-h, coalesced stores -------
__device__ __forceinline__ int xs_idx4(int s, int col4) {
    return s * 64 + (col4 ^ (s & 7));
}

__global__ __launch_bounds__(512, 4) void kv_kernel(
        const float* __restrict__ x, const unsigned short* __restrict__ WthA,
        const unsigned short* __restrict__ WtlA, const unsigned short* __restrict__ WvhA,
        unsigned short* __restrict__ Kh, unsigned short* __restrict__ Kl,
        unsigned short* __restrict__ Vt, int i0) {
    __shared__ unsigned xs[64 * 256];      // 64KB
    int bx = blockIdx.x & 255, i_local = blockIdx.x >> 8;
    int i = i0 + i_local;
    int b = bx >> 4, sb = bx & 15;
    int t = threadIdx.x, w = t >> 6, lane = t & 63, c = lane & 15, g = lane >> 4;
    int h = w;
    const unsigned short* wth = WthA + (size_t)i * 131072;
    const unsigned short* wtl = WtlA + (size_t)i * 131072;
    const unsigned short* wvh = WvhA + (size_t)i * 131072;
    unsigned short* Khp = Kh + (size_t)i_local * KSLOT;
    unsigned short* Klp = Kl + (size_t)i_local * KSLOT;
    unsigned short* Vtp = Vt + (size_t)i_local * KSLOT;

#pragma unroll
    for (int it = 0; it < 8; ++it) {
        int unit = t + it * 512;
        int ch = unit >> 4, sq = unit & 15;
        float4 v = *(const float4*)(x + ((size_t)b * Cc + ch) * Ss + sb * 64 + sq * 4);
        float vv[4] = {v.x, v.y, v.z, v.w};
#pragma unroll
        for (int e = 0; e < 4; ++e) {
            int s = sq * 4 + e;
            unsigned short hi = f2bf(vv[e]);
            unsigned short lo = f2bf(vv[e] - bf2f(hi));
            xs[s * 256 + ((ch >> 2) ^ (s & 7)) * 4 + (ch & 3)] =
                ((unsigned)hi << 16) | lo;
        }
    }
    __syncthreads();

    f32x4 accK[4][4], accV[4][4];
#pragma unroll
    for (int a = 0; a < 4; ++a)
#pragma unroll
      for (int s = 0; s < 4; ++s) {
        accK[a][s] = (f32x4){0.f, 0.f, 0.f, 0.f};
        accV[a][s] = (f32x4){0.f, 0.f, 0.f, 0.f};
      }

#pragma unroll
    for (int cs = 0; cs < 8; ++cs) {
        s16x8 xh[4], xl[4];
#pragma unroll
        for (int st = 0; st < 4; ++st) {
            int s = st * 16 + c;
            uint4 q0 = ((const uint4*)xs)[xs_idx4(s, cs * 8 + g * 2)];
            uint4 q1 = ((const uint4*)xs)[xs_idx4(s, cs * 8 + g * 2 + 1)];
            unsigned wrd[8] = {q0.x, q0.y, q0.z, q0.w, q1.x, q1.y, q1.z, q1.w};
            s16x8 fh, fl;
#pragma unroll
            for (int e = 0; e < 8; ++e) {
                fh[e] = (short)(wrd[e] >> 16);
                fl[e] = (short)(wrd[e] & 0xFFFF);
            }
            xh[st] = fh; xl[st] = fl;
        }
        int c0 = cs * 32 + g * 8;
#pragma unroll
        for (int nt = 0; nt < 4; ++nt) {
            int n = h * 64 + nt * 16 + c;
            s16x8 bh = __builtin_bit_cast(s16x8, *(const uint4*)(wth + (size_t)n * Cc + c0));
            s16x8 bl = __builtin_bit_cast(s16x8, *(const uint4*)(wtl + (size_t)n * Cc + c0));
            s16x8 bv = __builtin_bit_cast(s16x8, *(const uint4*)(wvh + (size_t)n * Cc + c0));
#pragma unroll
            for (int st = 0; st < 4; ++st) {
                accK[nt][st] = __builtin_amdgcn_mfma_f32_16x16x32_bf16(bh, xh[st], accK[nt][st], 0, 0, 0);
                accK[nt][st] = __builtin_amdgcn_mfma_f32_16x16x32_bf16(bh, xl[st], accK[nt][st], 0, 0, 0);
                accK[nt][st] = __builtin_amdgcn_mfma_f32_16x16x32_bf16(bl, xh[st], accK[nt][st], 0, 0, 0);
                accV[st][nt] = __builtin_amdgcn_mfma_f32_16x16x32_bf16(xh[st], bv, accV[st][nt], 0, 0, 0);
            }
        }
    }

#pragma unroll
    for (int nt = 0; nt < 4; ++nt)
#pragma unroll
      for (int st = 0; st < 4; ++st) {
        size_t kb = ((size_t)(b * Hh + h) * Ss + sb * 64 + st * 16 + c) * DHd
                    + nt * 16 + g * 4;
        unsigned short h0 = f2bf(accK[nt][st][0]), h1 = f2bf(accK[nt][st][1]);
        unsigned short h2 = f2bf(accK[nt][st][2]), h3 = f2bf(accK[nt][st][3]);
        uint2 ph; ph.x = h0 | ((unsigned)h1 << 16); ph.y = h2 | ((unsigned)h3 << 16);
        *(uint2*)(Khp + kb) = ph;
        unsigned short l0 = f2bf(accK[nt][st][0] - bf2f(h0));
        unsigned short l1 = f2bf(accK[nt][st][1] - bf2f(h1));
        unsigned short l2 = f2bf(accK[nt][st][2] - bf2f(h2));
        unsigned short l3 = f2bf(accK[nt][st][3] - bf2f(h3));
        uint2 pl; pl.x = l0 | ((unsigned)l1 << 16); pl.y = l2 | ((unsigned)l3 << 16);
        *(uint2*)(Klp + kb) = pl;
        size_t vb = ((size_t)(b * Hh + h) * DHd + nt * 16 + c) * Ss
                    + sb * 64 + st * 16 + g * 4;
        unsigned short v0 = f2bf(accV[st][nt][0]), v1 = f2bf(accV[st][nt][1]);
        unsigned short v2 = f2bf(accV[st][nt][2]), v3 = f2bf(accV[st][nt][3]);
        uint2 pv; pv.x = v0 | ((unsigned)v1 << 16); pv.y = v2 | ((unsigned)v3 << 16);
        *(uint2*)(Vtp + vb) = pv;
      }
}

// ---------- pass A: hi-only scores -> d = sum exp2(s), deferred reduce -------
__global__ __launch_bounds__(512, 4) void passA_kernel(
        const float* __restrict__ q, const unsigned short* __restrict__ Kh,
        float* __restrict__ md, int i0) {
    __shared__ unsigned short Klds[4096];
    int bx = blockIdx.x & 255, i_local = blockIdx.x >> 8;
    int i = i0 + i_local;
    int b = bx >> 4, h = (bx >> 1) & 7, sh = bx & 1;
    int t = threadIdx.x, p = t >> 6, lane = t & 63, c = lane & 15, g = lane >> 4;
    const float* qb = q + (size_t)i * QSLOT;
    const unsigned short* Khp = Kh + (size_t)i_local * KSLOT;

    s16x8 qh[4][2];
#pragma unroll
    for (int mt = 0; mt < 4; ++mt)
#pragma unroll
      for (int kt = 0; kt < 2; ++kt) {
        const float* qp = qb + (size_t)(p * 64 + mt * 16 + c) * INN + h * 64 + kt * 32 + g * 8;
        s16x8 f;
#pragma unroll
        for (int e = 0; e < 8; ++e) f[e] = (short)f2bf(qp[e] * KSC);
        qh[mt][kt] = f;
      }

    float d[4][4];
#pragma unroll
    for (int a = 0; a < 4; ++a)
#pragma unroll
      for (int r = 0; r < 4; ++r) d[a][r] = 0.f;

    int srow = t >> 3, g8 = t & 7, swz = g8 ^ (srow & 7);
    size_t rowb = (size_t)(b * Hh + h) * Ss;
    uint4 rK = *(const uint4*)(Khp + (rowb + sh * 512 + srow) * DHd + g8 * 8);

    for (int ch = 0; ch < 8; ++ch) {
        int sbase = sh * 512 + ch * 64;
        ((uint4*)Klds)[srow * 8 + swz] = rK;
        __syncthreads();
        if (ch < 7)
            rK = *(const uint4*)(Khp + (rowb + sbase + 64 + srow) * DHd + g8 * 8);

        f32x4 acc[4][4];
#pragma unroll
        for (int a = 0; a < 4; ++a)
#pragma unroll
          for (int s = 0; s < 4; ++s) acc[a][s] = (f32x4){0.f, 0.f, 0.f, 0.f};

#pragma unroll
        for (int kt = 0; kt < 2; ++kt)
#pragma unroll
          for (int st = 0; st < 4; ++st) {
            int srw = st * 16 + c;
            s16x8 kh = __builtin_bit_cast(s16x8,
                ((const uint4*)Klds)[srw * 8 + ((kt * 4 + g) ^ (srw & 7))]);
#pragma unroll
            for (int mt = 0; mt < 4; ++mt)
                acc[mt][st] = __builtin_amdgcn_mfma_f32_16x16x32_bf16(
                    qh[mt][kt], kh, acc[mt][st], 0, 0, 0);
          }

#pragma unroll
        for (int mt = 0; mt < 4; ++mt)
#pragma unroll
          for (int r = 0; r < 4; ++r)
            d[mt][r] += (__builtin_exp2f(acc[mt][0][r]) + __builtin_exp2f(acc[mt][1][r]))
                      + (__builtin_exp2f(acc[mt][2][r]) + __builtin_exp2f(acc[mt][3][r]));
        __syncthreads();
    }

    float* mdp = md + (size_t)i_local * MDSLOT;
#pragma unroll
    for (int mt = 0; mt < 4; ++mt)
#pragma unroll
      for (int r = 0; r < 4; ++r) {
        float v = d[mt][r];
        v += __shfl_xor(v, 1); v += __shfl_xor(v, 2);
        v += __shfl_xor(v, 4); v += __shfl_xor(v, 8);
        if (c == 0) {
            int row = mt * 16 + g * 4 + r;
            mdp[(((size_t)(b * Hh + h) * 2 + sh) * Pp + p) * Ll + row] = v;
        }
      }
}

// ---------- pass B: exact scores (3-mfma) -> probs, heat, PV (tr-read) -------
__global__ __launch_bounds__(512) void passB_kernel(
        const float* __restrict__ q, const unsigned short* __restrict__ Kh,
        const unsigned short* __restrict__ Kl, const unsigned short* __restrict__ Vt,
        const float* __restrict__ md, float* __restrict__ heatp,
        unsigned short* __restrict__ outp, int i0) {
    __shared__ unsigned short Khl_[4096];      // 8KB
    __shared__ unsigned short Kll_[4096];      // 8KB
    __shared__ unsigned short Vtl_[4096];      // 8KB
    __shared__ unsigned short plds[8 * 2048];  // 32KB, per-wave subtiled for tr
    int bx = blockIdx.x & 255, i_local = blockIdx.x >> 8;
    int i = i0 + i_local;
    int b = bx >> 4, h = (bx >> 1) & 7, sh = bx & 1;
    int t = threadIdx.x, p = t >> 6, lane = t & 63, c = lane & 15, g = lane >> 4;
    const float* qb = q + (size_t)i * QSLOT;
    const unsigned short* Khp = Kh + (size_t)i_local * KSLOT;
    const unsigned short* Klp = Kl + (size_t)i_local * KSLOT;
    const unsigned short* Vtp = Vt + (size_t)i_local * KSLOT;
    const float* mdp = md + (size_t)i_local * MDSLOT;
    float* hpp = heatp + (size_t)i_local * HEATSLOT;
    unsigned short* opp = outp + (size_t)i_local * OUTSLOT;

    float rdf[4][4];
#pragma unroll
    for (int mt = 0; mt < 4; ++mt)
#pragma unroll
      for (int r = 0; r < 4; ++r) {
        int row = mt * 16 + g * 4 + r;
        size_t j0 = (((size_t)(b * Hh + h) * 2 + 0) * Pp + p) * Ll + row;
        size_t j1 = (((size_t)(b * Hh + h) * 2 + 1) * Pp + p) * Ll + row;
        rdf[mt][r] = 1.0f / (mdp[j0] + mdp[j1]);
      }

    s16x8 qh[4][2], ql[4][2];
#pragma unroll
    for (int mt = 0; mt < 4; ++mt)
#pragma unroll
      for (int kt = 0; kt < 2; ++kt) {
        const float* qp = qb + (size_t)(p * 64 + mt * 16 + c) * INN + h * 64 + kt * 32 + g * 8;
        s16x8 fh, fl;
#pragma unroll
        for (int e = 0; e < 8; ++e) {
            float v = qp[e] * KSC;
            unsigned short hi = f2bf(v);
            fh[e] = (short)hi;
            fl[e] = (short)f2bf(v - bf2f(hi));
        }
        qh[mt][kt] = fh; ql[mt][kt] = fl;
      }

    f32x4 o[4][4];
#pragma unroll
    for (int a = 0; a < 4; ++a)
#pragma unroll
      for (int s = 0; s < 4; ++s) o[a][s] = (f32x4){0.f, 0.f, 0.f, 0.f};

    int srow = t >> 3, g8 = t & 7, swz = g8 ^ (srow & 7);
    size_t rowK = (size_t)(b * Hh + h) * Ss;
    size_t rowV = ((size_t)(b * Hh + h) * DHd + srow) * Ss;
    uint4 rK = *(const uint4*)(Khp + (rowK + sh * 512 + srow) * DHd + g8 * 8);
    uint4 rL = *(const uint4*)(Klp + (rowK + sh * 512 + srow) * DHd + g8 * 8);
    uint4 rV = *(const uint4*)(Vtp + rowV + sh * 512 + g8 * 8);

    unsigned short* pwb = plds + p * 2048 + ((c >> 2) & 1) * 256 + (c & 3) * 16 + g * 4;
    const unsigned short* trb = plds + p * 2048 + g * 64 + c;

    for (int ch = 0; ch < 8; ++ch) {
        int sbase = sh * 512 + ch * 64;
        int dst = srow * 8 + swz;
        ((uint4*)Khl_)[dst] = rK;
        ((uint4*)Kll_)[dst] = rL;
        ((uint4*)Vtl_)[dst] = rV;
        __syncthreads();
        if (ch < 7) {
            rK = *(const uint4*)(Khp + (rowK + sbase + 64 + srow) * DHd + g8 * 8);
            rL = *(const uint4*)(Klp + (rowK + sbase + 64 + srow) * DHd + g8 * 8);
            rV = *(const uint4*)(Vtp + rowV + sbase + 64 + g8 * 8);
        }

#pragma unroll
        for (int half = 0; half < 2; ++half) {
            f32x4 sacc[4][2];
#pragma unroll
            for (int a = 0; a < 4; ++a)
#pragma unroll
              for (int s = 0; s < 2; ++s) sacc[a][s] = (f32x4){0.f, 0.f, 0.f, 0.f};

#pragma unroll
            for (int kt = 0; kt < 2; ++kt)
#pragma unroll
              for (int s2 = 0; s2 < 2; ++s2) {
                int srw = (half * 2 + s2) * 16 + c;
                int gi = srw * 8 + ((kt * 4 + g) ^ (srw & 7));
                s16x8 kh = __builtin_bit_cast(s16x8, ((const uint4*)Khl_)[gi]);
                s16x8 kl = __builtin_bit_cast(s16x8, ((const uint4*)Kll_)[gi]);
#pragma unroll
                for (int mt = 0; mt < 4; ++mt) {
                    sacc[mt][s2] = __builtin_amdgcn_mfma_f32_16x16x32_bf16(
                        qh[mt][kt], kh, sacc[mt][s2], 0, 0, 0);
                    sacc[mt][s2] = __builtin_amdgcn_mfma_f32_16x16x32_bf16(
                        qh[mt][kt], kl, sacc[mt][s2], 0, 0, 0);
                    sacc[mt][s2] = __builtin_amdgcn_mfma_f32_16x16x32_bf16(
                        ql[mt][kt], kh, sacc[mt][s2], 0, 0, 0);
                }
              }

            // probs -> packed plds (tr-subtiled) + heat
#pragma unroll
            for (int s2 = 0; s2 < 2; ++s2) {
                float hs = 0.f;
#pragma unroll
                for (int mt = 0; mt < 4; ++mt) {
                    float pv0 = __builtin_exp2f(sacc[mt][s2][0]) * rdf[mt][0];
                    float pv1 = __builtin_exp2f(sacc[mt][s2][1]) * rdf[mt][1];
                    float pv2 = __builtin_exp2f(sacc[mt][s2][2]) * rdf[mt][2];
                    float pv3 = __builtin_exp2f(sacc[mt][s2][3]) * rdf[mt][3];
                    hs += (pv0 + pv1) + (pv2 + pv3);
                    uint2 pk;
                    pk.x = cvt_pk_bf16(pv0, pv1);
                    pk.y = cvt_pk_bf16(pv2, pv3);
                    *(uint2*)(pwb + mt * 512 + (s2 * 2 + (c >> 3)) * 64) = pk;
                }
                hs += __shfl_xor(hs, 16);
                hs += __shfl_xor(hs, 32);
                if (g == 0) {
                    int sgl = sbase + (half * 2 + s2) * 16 + c;
                    hpp[((size_t)(b * Pp + p) * Ss + sgl) * Hh + h] = hs;
                }
            }

            // PV via hardware transpose reads
            s16x8 vbf[4];
#pragma unroll
            for (int dht = 0; dht < 4; ++dht) {
                int row = dht * 16 + c;
                vbf[dht] = __builtin_bit_cast(s16x8,
                    ((const uint4*)Vtl_)[row * 8 + ((half * 4 + g) ^ (c & 7))]);
            }
            u32x2 ta[4][2];
#pragma unroll
            for (int mt = 0; mt < 4; ++mt) {
                ta[mt][0] = ds_tr16(trb + mt * 512);
                ta[mt][1] = ds_tr16(trb + mt * 512 + 256);
            }
            asm volatile("s_waitcnt lgkmcnt(0)" ::: "memory");
            __builtin_amdgcn_sched_barrier(0);
#pragma unroll
            for (int mt = 0; mt < 4; ++mt) {
                s16x8 pa = __builtin_bit_cast(s16x8,
                    (u32x4){ta[mt][0][0], ta[mt][0][1], ta[mt][1][0], ta[mt][1][1]});
#pragma unroll
                for (int dht = 0; dht < 4; ++dht)
                    o[mt][dht] = __builtin_amdgcn_mfma_f32_16x16x32_bf16(
                        pa, vbf[dht], o[mt][dht], 0, 0, 0);
            }
        }
        __syncthreads();
    }

#pragma unroll
    for (int mt = 0; mt < 4; ++mt)
#pragma unroll
      for (int dht = 0; dht < 4; ++dht)
#pragma unroll
        for (int r = 0; r < 4; ++r) {
            int row = mt * 16 + g * 4 + r;
            opp[(((((size_t)sh * Bq + b) * Hh + h) * Pp + p) * Ll + row) * DHd
                + dht * 16 + c] = f2bf(o[mt][dht][r]);
        }
}

// ---------- finalize: deterministic argmax + dist ----------------------------
__global__ __launch_bounds__(256) void fin_kernel(
        const float* __restrict__ heatp, const unsigned short* __restrict__ outp,
        const float* __restrict__ q, float* __restrict__ out, int i0) {
    __shared__ float rv[4];
    __shared__ int   ri[4];
    __shared__ float rs[4];
    int bx = blockIdx.x & 127, i_local = blockIdx.x >> 7;
    int i = i0 + i_local;
    int b = bx >> 3, p = bx & 7;
    int t = threadIdx.x, w = t >> 6, lane = t & 63;
    const float* qb = q + (size_t)i * QSLOT;
    const float* hp = heatp + (size_t)i_local * HEATSLOT;
    const unsigned short* ob = outp + (size_t)i_local * OUTSLOT;

    float best = -1e30f; int bidx = 0;
#pragma unroll
    for (int it = 0; it < 4; ++it) {
        int s = t + it * 256;
        const float* hv8 = hp + ((size_t)(b * Pp + p) * Ss + s) * Hh;
        float4 h0 = *(const float4*)hv8;
        float4 h1 = *(const float4*)(hv8 + 4);
        float hv = ((h0.x + h0.y) + (h0.z + h0.w)) + ((h1.x + h1.y) + (h1.z + h1.w));
        if (hv > best) { best = hv; bidx = s; }
    }
#pragma unroll
    for (int off = 1; off < 64; off <<= 1) {
        float vo = __shfl_xor(best, off);
        int   io = __shfl_xor(bidx, off);
        if (vo > best || (vo == best && io < bidx)) { best = vo; bidx = io; }
    }
    if (lane == 0) { rv[w] = best; ri[w] = bidx; }
    __syncthreads();
    if (t == 0) {
#pragma unroll
        for (int u = 1; u < 4; ++u)
            if (rv[u] > best || (rv[u] == best && ri[u] < bidx)) { best = rv[u]; bidx = ri[u]; }
        out[384 + b * 24 + i * Pp + p] = (float)bidx;
    }

    float sum = 0.f;
#pragma unroll 4
    for (int it = 0; it < 32; ++it) {
        int idx2 = t + it * 256;
        int dh4 = idx2 & 15, l = (idx2 >> 4) & 63, hh = idx2 >> 10;
        size_t base = ((size_t)((b * Hh + hh) * Pp + p) * 4096) + l * 64 + dh4 * 4;
        uint2 o0 = *(const uint2*)(ob + base);
        uint2 o1 = *(const uint2*)(ob + HALFO + base);
        float4 qv = *(const float4*)(qb + (size_t)(p * 64 + l) * INN + hh * 64 + dh4 * 4);
        float d0 = qv.x - (bf2f(o0.x & 0xFFFF) + bf2f(o1.x & 0xFFFF));
        float d1 = qv.y - (bf2f(o0.x >> 16)    + bf2f(o1.x >> 16));
        float d2 = qv.z - (bf2f(o0.y & 0xFFFF) + bf2f(o1.y & 0xFFFF));
        float d3 = qv.w - (bf2f(o0.y >> 16)    + bf2f(o1.y >> 16));
        sum += (d0 * d0 + d1 * d1) + (d2 * d2 + d3 * d3);
    }
#pragma unroll
    for (int off = 32; off; off >>= 1) sum += __shfl_down(sum, off);
    if (lane == 0) rs[w] = sum;
    __syncthreads();
    if (t == 0)
        out[b * 24 + i * Pp + p] = (rs[0] + rs[1] + rs[2] + rs[3]) / (float)(Ll * INN);
}

extern "C" void kernel_launch(void* const* d_in, const int* in_sizes, int n_in,
                              void* d_out, int out_size, void* d_ws, size_t ws_size,
                              hipStream_t stream) {
    const float* x    = (const float*)d_in[0];
    const float* prot = (const float*)d_in[1];
    const float* Wq   = (const float*)d_in[2];
    const float* Wk   = (const float*)d_in[3];
    const float* Wv   = (const float*)d_in[4];
    float* out = (float*)d_out;
    float* ws  = (float*)d_ws;

    // batched (3-slot) layout needs ~221 MB; fallback (1-slot) ~78 MB (proven to fit)
    const size_t needB = 220987392ull;
    bool batched = ws_size >= needB;
    size_t NS = batched ? 3 : 1;

    float* qbuf  = ws;                                   // 3*QSLOT f32 (always)
    float* md    = qbuf + 3 * QSLOT;                     // NS*MDSLOT
    float* heatp = md + NS * MDSLOT;                     // NS*HEATSLOT
    unsigned short* outp = (unsigned short*)(heatp + NS * HEATSLOT); // NS*OUTSLOT
    unsigned short* Kh  = outp + NS * OUTSLOT;           // NS*KSLOT
    unsigned short* Kl  = Kh + NS * KSLOT;
    unsigned short* Vt  = Kl + NS * KSLOT;
    unsigned short* Wth = Vt + NS * KSLOT;               // 3*WSLOT (always)
    unsigned short* Wtl = Wth + 3 * WSLOT;
    unsigned short* Wvh = Wtl + 3 * WSLOT;

    wsplit_kernel<<<192, 256, 0, stream>>>(Wk, Wv, Wth, Wtl, Wvh);
    qk_kernel    <<<384, 256, 0, stream>>>(prot, Wq, qbuf);
    if (batched) {
        kv_kernel   <<<768, 512, 0, stream>>>(x, Wth, Wtl, Wvh, Kh, Kl, Vt, 0);
        passA_kernel<<<768, 512, 0, stream>>>(qbuf, Kh, md, 0);
        passB_kernel<<<768, 512, 0, stream>>>(qbuf, Kh, Kl, Vt, md, heatp, outp, 0);
        fin_kernel  <<<384, 256, 0, stream>>>(heatp, outp, qbuf, out, 0);
    } else {
        for (int i = 0; i < 3; ++i) {
            kv_kernel   <<<256, 512, 0, stream>>>(x, Wth, Wtl, Wvh, Kh, Kl, Vt, i);
            passA_kernel<<<256, 512, 0, stream>>>(qbuf, Kh, md, i);
            passB_kernel<<<256, 512, 0, stream>>>(qbuf, Kh, Kl, Vt, md, heatp, outp, i);
            fin_kernel  <<<128, 256, 0, stream>>>(heatp, outp, qbuf, out, i);
        }
    }
}

// Round 6
// 405.140 us; speedup vs baseline: 1.9474x; 1.9474x over previous
//
#include <hip/hip_runtime.h>
#include <hip/hip_bf16.h>

#define Bq 16
#define Cc 256
#define Ss 1024
#define Ll 64
#define Hh 8
#define DHd 64
#define INN 512
#define Pp 8
// SCALE * log2(e) folded into q so scores are in log2 domain
#define KSC 0.18033688011111772f

// per-i slot sizes (elements)
#define QSLOT    262144
#define MDSLOT   131072
#define HEATSLOT 1048576
#define OUTSLOT  8388608
#define KSLOT    8388608
#define WSLOT    393216
#define HALFO    4194304

typedef short s16x8 __attribute__((ext_vector_type(8)));
typedef float f32x4 __attribute__((ext_vector_type(4)));
typedef unsigned u32x2 __attribute__((ext_vector_type(2)));
typedef unsigned u32x4 __attribute__((ext_vector_type(4)));

__device__ __forceinline__ unsigned short f2bf(float f) {
    unsigned u = __builtin_bit_cast(unsigned, f);
    u += 0x7FFF + ((u >> 16) & 1);
    return (unsigned short)(u >> 16);
}
__device__ __forceinline__ float bf2f(unsigned short h) {
    return __builtin_bit_cast(float, (unsigned)h << 16);
}
__device__ __forceinline__ unsigned cvt_pk_bf16(float a, float b) {
    unsigned r;
    asm volatile("v_cvt_pk_bf16_f32 %0, %1, %2" : "=v"(r) : "v"(a), "v"(b));
    return r;
}
__device__ __forceinline__ u32x2 ds_tr16(const unsigned short* p) {
    u32x2 d;
    asm volatile("ds_read_b64_tr_b16 %0, %1"
                 : "=v"(d)
                 : "v"((const __attribute__((address_space(3))) unsigned short*)p)
                 : "memory");
    return d;
}

// ---------- W transpose + bf16 hi/lo split ----------------------------------
__global__ __launch_bounds__(256) void wsplit_kernel(
        const float* __restrict__ Wk, const float* __restrict__ Wv,
        unsigned short* __restrict__ Wth, unsigned short* __restrict__ Wtl,
        unsigned short* __restrict__ Wvh) {
    __shared__ float tile[64][65];
    int blk = blockIdx.x;              // 192 = i*64 + mat*32 + ns*4 + cb
    int i = blk >> 6, rem = blk & 63, mat = rem >> 5, ns = (rem >> 2) & 7, cb = rem & 3;
    int n0 = ns * 64, c0 = cb * 64, t = threadIdx.x;
    const float* W = (mat == 0 ? Wk : Wv) + (size_t)i * Cc * INN;
#pragma unroll
    for (int it = 0; it < 16; ++it) {
        int idx = t + it * 256; int cc = idx >> 6, nn = idx & 63;
        tile[cc][nn] = W[(size_t)(c0 + cc) * INN + n0 + nn];
    }
    __syncthreads();
#pragma unroll
    for (int it = 0; it < 16; ++it) {
        int idx = t + it * 256; int nn = idx >> 6, cc = idx & 63;
        float v = tile[cc][nn];
        unsigned short hi = f2bf(v);
        size_t o = (size_t)i * 131072 + (size_t)(n0 + nn) * Cc + c0 + cc;
        if (mat == 0) { Wth[o] = hi; Wtl[o] = f2bf(v - bf2f(hi)); }
        else          { Wvh[o] = hi; }
    }
}

// ---------- q = pp @ Wq[i] : f32, 4 l-rows per block for W reuse -------------
__global__ __launch_bounds__(256) void qk_kernel(const float* __restrict__ prot,
                                                 const float* __restrict__ Wq,
                                                 float* __restrict__ qout) {
    __shared__ float pcol[4][256];
    int blk = blockIdx.x;              // 384 = i*128 + p*16 + l4
    int i = blk >> 7, rem = blk & 127, p = rem >> 4, l4 = rem & 15;
    int t = threadIdx.x;
    const float* W = Wq + (size_t)i * Cc * INN;
#pragma unroll
    for (int it = 0; it < 4; ++it) {
        int idx = t + it * 256; int ll = idx >> 8, cc = idx & 255;
        pcol[ll][cc] = prot[((size_t)(i * Pp + p) * Cc + cc) * Ll + l4 * 4 + ll];
    }
    __syncthreads();
    float a0[4] = {0, 0, 0, 0}, a1[4] = {0, 0, 0, 0};
#pragma unroll 4
    for (int c = 0; c < Cc; ++c) {
        float w0 = W[c * INN + t], w1 = W[c * INN + t + 256];
#pragma unroll
        for (int ll = 0; ll < 4; ++ll) {
            a0[ll] += pcol[ll][c] * w0;
            a1[ll] += pcol[ll][c] * w1;
        }
    }
#pragma unroll
    for (int ll = 0; ll < 4; ++ll) {
        float* qo = qout + (size_t)i * QSLOT + (size_t)(p * 64 + l4 * 4 + ll) * INN;
        qo[t] = a0[ll]; qo[t + 256] = a1[ll];
    }
}

// ---------- K,V projection: x LDS-staged, wave-per-h, coalesced stores -------
// NOTE: launch_bounds min-waves MUST stay 2 — accK+accV need 128 VGPRs;
// (512,4) caps at 64 VGPR and spills accumulators to scratch (r5: 1.5GB HBM).
__device__ __forceinline__ int xs_idx4(int s, int col4) {
    return s * 64 + (col4 ^ (s & 7));
}

__global__ __launch_bounds__(512, 2) void kv_kernel(
        const float* __restrict__ x, const unsigned short* __restrict__ WthA,
        const unsigned short* __restrict__ WtlA, const unsigned short* __restrict__ WvhA,
        unsigned short* __restrict__ Kh, unsigned short* __restrict__ Kl,
        unsigned short* __restrict__ Vt, int i0) {
    __shared__ unsigned xs[64 * 256];      // 64KB
    int bx = blockIdx.x & 255, i_local = blockIdx.x >> 8;
    int i = i0 + i_local;
    int b = bx >> 4, sb = bx & 15;
    int t = threadIdx.x, w = t >> 6, lane = t & 63, c = lane & 15, g = lane >> 4;
    int h = w;
    const unsigned short* wth = WthA + (size_t)i * 131072;
    const unsigned short* wtl = WtlA + (size_t)i * 131072;
    const unsigned short* wvh = WvhA + (size_t)i * 131072;
    unsigned short* Khp = Kh + (size_t)i_local * KSLOT;
    unsigned short* Klp = Kl + (size_t)i_local * KSLOT;
    unsigned short* Vtp = Vt + (size_t)i_local * KSLOT;

#pragma unroll
    for (int it = 0; it < 8; ++it) {
        int unit = t + it * 512;
        int ch = unit >> 4, sq = unit & 15;
        float4 v = *(const float4*)(x + ((size_t)b * Cc + ch) * Ss + sb * 64 + sq * 4);
        float vv[4] = {v.x, v.y, v.z, v.w};
#pragma unroll
        for (int e = 0; e < 4; ++e) {
            int s = sq * 4 + e;
            unsigned short hi = f2bf(vv[e]);
            unsigned short lo = f2bf(vv[e] - bf2f(hi));
            xs[s * 256 + ((ch >> 2) ^ (s & 7)) * 4 + (ch & 3)] =
                ((unsigned)hi << 16) | lo;
        }
    }
    __syncthreads();

    f32x4 accK[4][4], accV[4][4];
#pragma unroll
    for (int a = 0; a < 4; ++a)
#pragma unroll
      for (int s = 0; s < 4; ++s) {
        accK[a][s] = (f32x4){0.f, 0.f, 0.f, 0.f};
        accV[a][s] = (f32x4){0.f, 0.f, 0.f, 0.f};
      }

#pragma unroll
    for (int cs = 0; cs < 8; ++cs) {
        s16x8 xh[4], xl[4];
#pragma unroll
        for (int st = 0; st < 4; ++st) {
            int s = st * 16 + c;
            uint4 q0 = ((const uint4*)xs)[xs_idx4(s, cs * 8 + g * 2)];
            uint4 q1 = ((const uint4*)xs)[xs_idx4(s, cs * 8 + g * 2 + 1)];
            unsigned wrd[8] = {q0.x, q0.y, q0.z, q0.w, q1.x, q1.y, q1.z, q1.w};
            s16x8 fh, fl;
#pragma unroll
            for (int e = 0; e < 8; ++e) {
                fh[e] = (short)(wrd[e] >> 16);
                fl[e] = (short)(wrd[e] & 0xFFFF);
            }
            xh[st] = fh; xl[st] = fl;
        }
        int c0 = cs * 32 + g * 8;
#pragma unroll
        for (int nt = 0; nt < 4; ++nt) {
            int n = h * 64 + nt * 16 + c;
            s16x8 bh = __builtin_bit_cast(s16x8, *(const uint4*)(wth + (size_t)n * Cc + c0));
            s16x8 bl = __builtin_bit_cast(s16x8, *(const uint4*)(wtl + (size_t)n * Cc + c0));
            s16x8 bv = __builtin_bit_cast(s16x8, *(const uint4*)(wvh + (size_t)n * Cc + c0));
#pragma unroll
            for (int st = 0; st < 4; ++st) {
                accK[nt][st] = __builtin_amdgcn_mfma_f32_16x16x32_bf16(bh, xh[st], accK[nt][st], 0, 0, 0);
                accK[nt][st] = __builtin_amdgcn_mfma_f32_16x16x32_bf16(bh, xl[st], accK[nt][st], 0, 0, 0);
                accK[nt][st] = __builtin_amdgcn_mfma_f32_16x16x32_bf16(bl, xh[st], accK[nt][st], 0, 0, 0);
                accV[st][nt] = __builtin_amdgcn_mfma_f32_16x16x32_bf16(xh[st], bv, accV[st][nt], 0, 0, 0);
            }
        }
    }

#pragma unroll
    for (int nt = 0; nt < 4; ++nt)
#pragma unroll
      for (int st = 0; st < 4; ++st) {
        size_t kb = ((size_t)(b * Hh + h) * Ss + sb * 64 + st * 16 + c) * DHd
                    + nt * 16 + g * 4;
        unsigned short h0 = f2bf(accK[nt][st][0]), h1 = f2bf(accK[nt][st][1]);
        unsigned short h2 = f2bf(accK[nt][st][2]), h3 = f2bf(accK[nt][st][3]);
        uint2 ph; ph.x = h0 | ((unsigned)h1 << 16); ph.y = h2 | ((unsigned)h3 << 16);
        *(uint2*)(Khp + kb) = ph;
        unsigned short l0 = f2bf(accK[nt][st][0] - bf2f(h0));
        unsigned short l1 = f2bf(accK[nt][st][1] - bf2f(h1));
        unsigned short l2 = f2bf(accK[nt][st][2] - bf2f(h2));
        unsigned short l3 = f2bf(accK[nt][st][3] - bf2f(h3));
        uint2 pl; pl.x = l0 | ((unsigned)l1 << 16); pl.y = l2 | ((unsigned)l3 << 16);
        *(uint2*)(Klp + kb) = pl;
        size_t vb = ((size_t)(b * Hh + h) * DHd + nt * 16 + c) * Ss
                    + sb * 64 + st * 16 + g * 4;
        unsigned short v0 = f2bf(accV[st][nt][0]), v1 = f2bf(accV[st][nt][1]);
        unsigned short v2 = f2bf(accV[st][nt][2]), v3 = f2bf(accV[st][nt][3]);
        uint2 pv; pv.x = v0 | ((unsigned)v1 << 16); pv.y = v2 | ((unsigned)v3 << 16);
        *(uint2*)(Vtp + vb) = pv;
      }
}

// ---------- pass A: hi-only scores -> d = sum exp2(s), deferred reduce -------
__global__ __launch_bounds__(512, 2) void passA_kernel(
        const float* __restrict__ q, const unsigned short* __restrict__ Kh,
        float* __restrict__ md, int i0) {
    __shared__ unsigned short Klds[4096];
    int bx = blockIdx.x & 255, i_local = blockIdx.x >> 8;
    int i = i0 + i_local;
    int b = bx >> 4, h = (bx >> 1) & 7, sh = bx & 1;
    int t = threadIdx.x, p = t >> 6, lane = t & 63, c = lane & 15, g = lane >> 4;
    const float* qb = q + (size_t)i * QSLOT;
    const unsigned short* Khp = Kh + (size_t)i_local * KSLOT;

    s16x8 qh[4][2];
#pragma unroll
    for (int mt = 0; mt < 4; ++mt)
#pragma unroll
      for (int kt = 0; kt < 2; ++kt) {
        const float* qp = qb + (size_t)(p * 64 + mt * 16 + c) * INN + h * 64 + kt * 32 + g * 8;
        s16x8 f;
#pragma unroll
        for (int e = 0; e < 8; ++e) f[e] = (short)f2bf(qp[e] * KSC);
        qh[mt][kt] = f;
      }

    float d[4][4];
#pragma unroll
    for (int a = 0; a < 4; ++a)
#pragma unroll
      for (int r = 0; r < 4; ++r) d[a][r] = 0.f;

    int srow = t >> 3, g8 = t & 7, swz = g8 ^ (srow & 7);
    size_t rowb = (size_t)(b * Hh + h) * Ss;
    uint4 rK = *(const uint4*)(Khp + (rowb + sh * 512 + srow) * DHd + g8 * 8);

    for (int ch = 0; ch < 8; ++ch) {
        int sbase = sh * 512 + ch * 64;
        ((uint4*)Klds)[srow * 8 + swz] = rK;
        __syncthreads();
        if (ch < 7)
            rK = *(const uint4*)(Khp + (rowb + sbase + 64 + srow) * DHd + g8 * 8);

        f32x4 acc[4][4];
#pragma unroll
        for (int a = 0; a < 4; ++a)
#pragma unroll
          for (int s = 0; s < 4; ++s) acc[a][s] = (f32x4){0.f, 0.f, 0.f, 0.f};

#pragma unroll
        for (int kt = 0; kt < 2; ++kt)
#pragma unroll
          for (int st = 0; st < 4; ++st) {
            int srw = st * 16 + c;
            s16x8 kh = __builtin_bit_cast(s16x8,
                ((const uint4*)Klds)[srw * 8 + ((kt * 4 + g) ^ (srw & 7))]);
#pragma unroll
            for (int mt = 0; mt < 4; ++mt)
                acc[mt][st] = __builtin_amdgcn_mfma_f32_16x16x32_bf16(
                    qh[mt][kt], kh, acc[mt][st], 0, 0, 0);
          }

#pragma unroll
        for (int mt = 0; mt < 4; ++mt)
#pragma unroll
          for (int r = 0; r < 4; ++r)
            d[mt][r] += (__builtin_exp2f(acc[mt][0][r]) + __builtin_exp2f(acc[mt][1][r]))
                      + (__builtin_exp2f(acc[mt][2][r]) + __builtin_exp2f(acc[mt][3][r]));
        __syncthreads();
    }

    float* mdp = md + (size_t)i_local * MDSLOT;
#pragma unroll
    for (int mt = 0; mt < 4; ++mt)
#pragma unroll
      for (int r = 0; r < 4; ++r) {
        float v = d[mt][r];
        v += __shfl_xor(v, 1); v += __shfl_xor(v, 2);
        v += __shfl_xor(v, 4); v += __shfl_xor(v, 8);
        if (c == 0) {
            int row = mt * 16 + g * 4 + r;
            mdp[(((size_t)(b * Hh + h) * 2 + sh) * Pp + p) * Ll + row] = v;
        }
      }
}

// ---------- pass B: exact scores (3-mfma) -> probs, heat, PV (tr-read) -------
__global__ __launch_bounds__(512) void passB_kernel(
        const float* __restrict__ q, const unsigned short* __restrict__ Kh,
        const unsigned short* __restrict__ Kl, const unsigned short* __restrict__ Vt,
        const float* __restrict__ md, float* __restrict__ heatp,
        unsigned short* __restrict__ outp, int i0) {
    __shared__ unsigned short Khl_[4096];      // 8KB
    __shared__ unsigned short Kll_[4096];      // 8KB
    __shared__ unsigned short Vtl_[4096];      // 8KB
    __shared__ unsigned short plds[8 * 2048];  // 32KB, per-wave subtiled for tr
    int bx = blockIdx.x & 255, i_local = blockIdx.x >> 8;
    int i = i0 + i_local;
    int b = bx >> 4, h = (bx >> 1) & 7, sh = bx & 1;
    int t = threadIdx.x, p = t >> 6, lane = t & 63, c = lane & 15, g = lane >> 4;
    const float* qb = q + (size_t)i * QSLOT;
    const unsigned short* Khp = Kh + (size_t)i_local * KSLOT;
    const unsigned short* Klp = Kl + (size_t)i_local * KSLOT;
    const unsigned short* Vtp = Vt + (size_t)i_local * KSLOT;
    const float* mdp = md + (size_t)i_local * MDSLOT;
    float* hpp = heatp + (size_t)i_local * HEATSLOT;
    unsigned short* opp = outp + (size_t)i_local * OUTSLOT;

    float rdf[4][4];
#pragma unroll
    for (int mt = 0; mt < 4; ++mt)
#pragma unroll
      for (int r = 0; r < 4; ++r) {
        int row = mt * 16 + g * 4 + r;
        size_t j0 = (((size_t)(b * Hh + h) * 2 + 0) * Pp + p) * Ll + row;
        size_t j1 = (((size_t)(b * Hh + h) * 2 + 1) * Pp + p) * Ll + row;
        rdf[mt][r] = 1.0f / (mdp[j0] + mdp[j1]);
      }

    s16x8 qh[4][2], ql[4][2];
#pragma unroll
    for (int mt = 0; mt < 4; ++mt)
#pragma unroll
      for (int kt = 0; kt < 2; ++kt) {
        const float* qp = qb + (size_t)(p * 64 + mt * 16 + c) * INN + h * 64 + kt * 32 + g * 8;
        s16x8 fh, fl;
#pragma unroll
        for (int e = 0; e < 8; ++e) {
            float v = qp[e] * KSC;
            unsigned short hi = f2bf(v);
            fh[e] = (short)hi;
            fl[e] = (short)f2bf(v - bf2f(hi));
        }
        qh[mt][kt] = fh; ql[mt][kt] = fl;
      }

    f32x4 o[4][4];
#pragma unroll
    for (int a = 0; a < 4; ++a)
#pragma unroll
      for (int s = 0; s < 4; ++s) o[a][s] = (f32x4){0.f, 0.f, 0.f, 0.f};

    int srow = t >> 3, g8 = t & 7, swz = g8 ^ (srow & 7);
    size_t rowK = (size_t)(b * Hh + h) * Ss;
    size_t rowV = ((size_t)(b * Hh + h) * DHd + srow) * Ss;
    uint4 rK = *(const uint4*)(Khp + (rowK + sh * 512 + srow) * DHd + g8 * 8);
    uint4 rL = *(const uint4*)(Klp + (rowK + sh * 512 + srow) * DHd + g8 * 8);
    uint4 rV = *(const uint4*)(Vtp + rowV + sh * 512 + g8 * 8);

    unsigned short* pwb = plds + p * 2048 + ((c >> 2) & 1) * 256 + (c & 3) * 16 + g * 4;
    const unsigned short* trb = plds + p * 2048 + g * 64 + c;

    for (int ch = 0; ch < 8; ++ch) {
        int sbase = sh * 512 + ch * 64;
        int dst = srow * 8 + swz;
        ((uint4*)Khl_)[dst] = rK;
        ((uint4*)Kll_)[dst] = rL;
        ((uint4*)Vtl_)[dst] = rV;
        __syncthreads();
        if (ch < 7) {
            rK = *(const uint4*)(Khp + (rowK + sbase + 64 + srow) * DHd + g8 * 8);
            rL = *(const uint4*)(Klp + (rowK + sbase + 64 + srow) * DHd + g8 * 8);
            rV = *(const uint4*)(Vtp + rowV + sbase + 64 + g8 * 8);
        }

#pragma unroll
        for (int half = 0; half < 2; ++half) {
            f32x4 sacc[4][2];
#pragma unroll
            for (int a = 0; a < 4; ++a)
#pragma unroll
              for (int s = 0; s < 2; ++s) sacc[a][s] = (f32x4){0.f, 0.f, 0.f, 0.f};

#pragma unroll
            for (int kt = 0; kt < 2; ++kt)
#pragma unroll
              for (int s2 = 0; s2 < 2; ++s2) {
                int srw = (half * 2 + s2) * 16 + c;
                int gi = srw * 8 + ((kt * 4 + g) ^ (srw & 7));
                s16x8 kh = __builtin_bit_cast(s16x8, ((const uint4*)Khl_)[gi]);
                s16x8 kl = __builtin_bit_cast(s16x8, ((const uint4*)Kll_)[gi]);
#pragma unroll
                for (int mt = 0; mt < 4; ++mt) {
                    sacc[mt][s2] = __builtin_amdgcn_mfma_f32_16x16x32_bf16(
                        qh[mt][kt], kh, sacc[mt][s2], 0, 0, 0);
                    sacc[mt][s2] = __builtin_amdgcn_mfma_f32_16x16x32_bf16(
                        qh[mt][kt], kl, sacc[mt][s2], 0, 0, 0);
                    sacc[mt][s2] = __builtin_amdgcn_mfma_f32_16x16x32_bf16(
                        ql[mt][kt], kh, sacc[mt][s2], 0, 0, 0);
                }
              }

            // probs -> packed plds (tr-subtiled) + heat
#pragma unroll
            for (int s2 = 0; s2 < 2; ++s2) {
                float hs = 0.f;
#pragma unroll
                for (int mt = 0; mt < 4; ++mt) {
                    float pv0 = __builtin_exp2f(sacc[mt][s2][0]) * rdf[mt][0];
                    float pv1 = __builtin_exp2f(sacc[mt][s2][1]) * rdf[mt][1];
                    float pv2 = __builtin_exp2f(sacc[mt][s2][2]) * rdf[mt][2];
                    float pv3 = __builtin_exp2f(sacc[mt][s2][3]) * rdf[mt][3];
                    hs += (pv0 + pv1) + (pv2 + pv3);
                    uint2 pk;
                    pk.x = cvt_pk_bf16(pv0, pv1);
                    pk.y = cvt_pk_bf16(pv2, pv3);
                    *(uint2*)(pwb + mt * 512 + (s2 * 2 + (c >> 3)) * 64) = pk;
                }
                hs += __shfl_xor(hs, 16);
                hs += __shfl_xor(hs, 32);
                if (g == 0) {
                    int sgl = sbase + (half * 2 + s2) * 16 + c;
                    hpp[((size_t)(b * Pp + p) * Ss + sgl) * Hh + h] = hs;
                }
            }

            // PV via hardware transpose reads
            s16x8 vbf[4];
#pragma unroll
            for (int dht = 0; dht < 4; ++dht) {
                int row = dht * 16 + c;
                vbf[dht] = __builtin_bit_cast(s16x8,
                    ((const uint4*)Vtl_)[row * 8 + ((half * 4 + g) ^ (c & 7))]);
            }
            u32x2 ta[4][2];
#pragma unroll
            for (int mt = 0; mt < 4; ++mt) {
                ta[mt][0] = ds_tr16(trb + mt * 512);
                ta[mt][1] = ds_tr16(trb + mt * 512 + 256);
            }
            asm volatile("s_waitcnt lgkmcnt(0)" ::: "memory");
            __builtin_amdgcn_sched_barrier(0);
#pragma unroll
            for (int mt = 0; mt < 4; ++mt) {
                s16x8 pa = __builtin_bit_cast(s16x8,
                    (u32x4){ta[mt][0][0], ta[mt][0][1], ta[mt][1][0], ta[mt][1][1]});
#pragma unroll
                for (int dht = 0; dht < 4; ++dht)
                    o[mt][dht] = __builtin_amdgcn_mfma_f32_16x16x32_bf16(
                        pa, vbf[dht], o[mt][dht], 0, 0, 0);
            }
        }
        __syncthreads();
    }

#pragma unroll
    for (int mt = 0; mt < 4; ++mt)
#pragma unroll
      for (int dht = 0; dht < 4; ++dht)
#pragma unroll
        for (int r = 0; r < 4; ++r) {
            int row = mt * 16 + g * 4 + r;
            opp[(((((size_t)sh * Bq + b) * Hh + h) * Pp + p) * Ll + row) * DHd
                + dht * 16 + c] = f2bf(o[mt][dht][r]);
        }
}

// ---------- finalize: deterministic argmax + dist ----------------------------
__global__ __launch_bounds__(256) void fin_kernel(
        const float* __restrict__ heatp, const unsigned short* __restrict__ outp,
        const float* __restrict__ q, float* __restrict__ out, int i0) {
    __shared__ float rv[4];
    __shared__ int   ri[4];
    __shared__ float rs[4];
    int bx = blockIdx.x & 127, i_local = blockIdx.x >> 7;
    int i = i0 + i_local;
    int b = bx >> 3, p = bx & 7;
    int t = threadIdx.x, w = t >> 6, lane = t & 63;
    const float* qb = q + (size_t)i * QSLOT;
    const float* hp = heatp + (size_t)i_local * HEATSLOT;
    const unsigned short* ob = outp + (size_t)i_local * OUTSLOT;

    float best = -1e30f; int bidx = 0;
#pragma unroll
    for (int it = 0; it < 4; ++it) {
        int s = t + it * 256;
        const float* hv8 = hp + ((size_t)(b * Pp + p) * Ss + s) * Hh;
        float4 h0 = *(const float4*)hv8;
        float4 h1 = *(const float4*)(hv8 + 4);
        float hv = ((h0.x + h0.y) + (h0.z + h0.w)) + ((h1.x + h1.y) + (h1.z + h1.w));
        if (hv > best) { best = hv; bidx = s; }
    }
#pragma unroll
    for (int off = 1; off < 64; off <<= 1) {
        float vo = __shfl_xor(best, off);
        int   io = __shfl_xor(bidx, off);
        if (vo > best || (vo == best && io < bidx)) { best = vo; bidx = io; }
    }
    if (lane == 0) { rv[w] = best; ri[w] = bidx; }
    __syncthreads();
    if (t == 0) {
#pragma unroll
        for (int u = 1; u < 4; ++u)
            if (rv[u] > best || (rv[u] == best && ri[u] < bidx)) { best = rv[u]; bidx = ri[u]; }
        out[384 + b * 24 + i * Pp + p] = (float)bidx;
    }

    float sum = 0.f;
#pragma unroll 4
    for (int it = 0; it < 32; ++it) {
        int idx2 = t + it * 256;
        int dh4 = idx2 & 15, l = (idx2 >> 4) & 63, hh = idx2 >> 10;
        size_t base = ((size_t)((b * Hh + hh) * Pp + p) * 4096) + l * 64 + dh4 * 4;
        uint2 o0 = *(const uint2*)(ob + base);
        uint2 o1 = *(const uint2*)(ob + HALFO + base);
        float4 qv = *(const float4*)(qb + (size_t)(p * 64 + l) * INN + hh * 64 + dh4 * 4);
        float d0 = qv.x - (bf2f(o0.x & 0xFFFF) + bf2f(o1.x & 0xFFFF));
        float d1 = qv.y - (bf2f(o0.x >> 16)    + bf2f(o1.x >> 16));
        float d2 = qv.z - (bf2f(o0.y & 0xFFFF) + bf2f(o1.y & 0xFFFF));
        float d3 = qv.w - (bf2f(o0.y >> 16)    + bf2f(o1.y >> 16));
        sum += (d0 * d0 + d1 * d1) + (d2 * d2 + d3 * d3);
    }
#pragma unroll
    for (int off = 32; off; off >>= 1) sum += __shfl_down(sum, off);
    if (lane == 0) rs[w] = sum;
    __syncthreads();
    if (t == 0)
        out[b * 24 + i * Pp + p] = (rs[0] + rs[1] + rs[2] + rs[3]) / (float)(Ll * INN);
}

extern "C" void kernel_launch(void* const* d_in, const int* in_sizes, int n_in,
                              void* d_out, int out_size, void* d_ws, size_t ws_size,
                              hipStream_t stream) {
    const float* x    = (const float*)d_in[0];
    const float* prot = (const float*)d_in[1];
    const float* Wq   = (const float*)d_in[2];
    const float* Wk   = (const float*)d_in[3];
    const float* Wv   = (const float*)d_in[4];
    float* out = (float*)d_out;
    float* ws  = (float*)d_ws;

    // batched (3-slot) layout needs ~221 MB; fallback (1-slot) ~78 MB
    const size_t needB = 220987392ull;
    bool batched = ws_size >= needB;
    size_t NS = batched ? 3 : 1;

    float* qbuf  = ws;                                   // 3*QSLOT f32 (always)
    float* md    = qbuf + 3 * QSLOT;                     // NS*MDSLOT
    float* heatp = md + NS * MDSLOT;                     // NS*HEATSLOT
    unsigned short* outp = (unsigned short*)(heatp + NS * HEATSLOT); // NS*OUTSLOT
    unsigned short* Kh  = outp + NS * OUTSLOT;           // NS*KSLOT
    unsigned short* Kl  = Kh + NS * KSLOT;
    unsigned short* Vt  = Kl + NS * KSLOT;
    unsigned short* Wth = Vt + NS * KSLOT;               // 3*WSLOT (always)
    unsigned short* Wtl = Wth + 3 * WSLOT;
    unsigned short* Wvh = Wtl + 3 * WSLOT;

    wsplit_kernel<<<192, 256, 0, stream>>>(Wk, Wv, Wth, Wtl, Wvh);
    qk_kernel    <<<384, 256, 0, stream>>>(prot, Wq, qbuf);
    if (batched) {
        kv_kernel   <<<768, 512, 0, stream>>>(x, Wth, Wtl, Wvh, Kh, Kl, Vt, 0);
        passA_kernel<<<768, 512, 0, stream>>>(qbuf, Kh, md, 0);
        passB_kernel<<<768, 512, 0, stream>>>(qbuf, Kh, Kl, Vt, md, heatp, outp, 0);
        fin_kernel  <<<384, 256, 0, stream>>>(heatp, outp, qbuf, out, 0);
    } else {
        for (int i = 0; i < 3; ++i) {
            kv_kernel   <<<256, 512, 0, stream>>>(x, Wth, Wtl, Wvh, Kh, Kl, Vt, i);
            passA_kernel<<<256, 512, 0, stream>>>(qbuf, Kh, md, i);
            passB_kernel<<<256, 512, 0, stream>>>(qbuf, Kh, Kl, Vt, md, heatp, outp, i);
            fin_kernel  <<<128, 256, 0, stream>>>(heatp, outp, qbuf, out, i);
        }
    }
}

// Round 7
// 356.042 us; speedup vs baseline: 2.2160x; 1.1379x over previous
//
#include <hip/hip_runtime.h>
#include <hip/hip_bf16.h>

#define Bq 16
#define Cc 256
#define Ss 1024
#define Ll 64
#define Hh 8
#define DHd 64
#define INN 512
#define Pp 8
// SCALE * log2(e) folded into q so scores are in log2 domain
#define KSC 0.18033688011111772f

// per-i slot sizes (elements)
#define QSLOT    262144
#define MDSLOT   131072
#define HEATSLOT 1048576
#define OUTSLOT  8388608
#define KSLOT    8388608
#define WSLOT    393216
#define HALFO    4194304

typedef _Float16 f16x8 __attribute__((ext_vector_type(8)));
typedef _Float16 f16x2 __attribute__((ext_vector_type(2)));
typedef float f32x4 __attribute__((ext_vector_type(4)));
typedef unsigned u32x2 __attribute__((ext_vector_type(2)));
typedef unsigned u32x4 __attribute__((ext_vector_type(4)));

__device__ __forceinline__ unsigned short f2bf(float f) {
    unsigned u = __builtin_bit_cast(unsigned, f);
    u += 0x7FFF + ((u >> 16) & 1);
    return (unsigned short)(u >> 16);
}
__device__ __forceinline__ float bf2f(unsigned short h) {
    return __builtin_bit_cast(float, (unsigned)h << 16);
}
__device__ __forceinline__ unsigned short f2h(float f) {      // RTN
    _Float16 h = (_Float16)f;
    return __builtin_bit_cast(unsigned short, h);
}
__device__ __forceinline__ u32x2 ds_tr16(const unsigned short* p) {
    u32x2 d;
    asm volatile("ds_read_b64_tr_b16 %0, %1"
                 : "=v"(d)
                 : "v"((const __attribute__((address_space(3))) unsigned short*)p)
                 : "memory");
    return d;
}

// ---------- W transpose + f16 convert: Wk -> Wth, Wv -> Wvh ------------------
__global__ __launch_bounds__(256) void wsplit_kernel(
        const float* __restrict__ Wk, const float* __restrict__ Wv,
        unsigned short* __restrict__ Wth, unsigned short* __restrict__ Wvh) {
    __shared__ float tile[64][65];
    int blk = blockIdx.x;              // 192 = i*64 + mat*32 + ns*4 + cb
    int i = blk >> 6, rem = blk & 63, mat = rem >> 5, ns = (rem >> 2) & 7, cb = rem & 3;
    int n0 = ns * 64, c0 = cb * 64, t = threadIdx.x;
    const float* W = (mat == 0 ? Wk : Wv) + (size_t)i * Cc * INN;
#pragma unroll
    for (int it = 0; it < 16; ++it) {
        int idx = t + it * 256; int cc = idx >> 6, nn = idx & 63;
        tile[cc][nn] = W[(size_t)(c0 + cc) * INN + n0 + nn];
    }
    __syncthreads();
#pragma unroll
    for (int it = 0; it < 16; ++it) {
        int idx = t + it * 256; int nn = idx >> 6, cc = idx & 63;
        float v = tile[cc][nn];
        size_t o = (size_t)i * 131072 + (size_t)(n0 + nn) * Cc + c0 + cc;
        if (mat == 0) Wth[o] = f2h(v);
        else          Wvh[o] = f2h(v);
    }
}

// ---------- q = pp @ Wq[i] : f32, 4 l-rows per block for W reuse -------------
__global__ __launch_bounds__(256) void qk_kernel(const float* __restrict__ prot,
                                                 const float* __restrict__ Wq,
                                                 float* __restrict__ qout) {
    __shared__ float pcol[4][256];
    int blk = blockIdx.x;              // 384 = i*128 + p*16 + l4
    int i = blk >> 7, rem = blk & 127, p = rem >> 4, l4 = rem & 15;
    int t = threadIdx.x;
    const float* W = Wq + (size_t)i * Cc * INN;
#pragma unroll
    for (int it = 0; it < 4; ++it) {
        int idx = t + it * 256; int ll = idx >> 8, cc = idx & 255;
        pcol[ll][cc] = prot[((size_t)(i * Pp + p) * Cc + cc) * Ll + l4 * 4 + ll];
    }
    __syncthreads();
    float a0[4] = {0, 0, 0, 0}, a1[4] = {0, 0, 0, 0};
#pragma unroll 4
    for (int c = 0; c < Cc; ++c) {
        float w0 = W[c * INN + t], w1 = W[c * INN + t + 256];
#pragma unroll
        for (int ll = 0; ll < 4; ++ll) {
            a0[ll] += pcol[ll][c] * w0;
            a1[ll] += pcol[ll][c] * w1;
        }
    }
#pragma unroll
    for (int ll = 0; ll < 4; ++ll) {
        float* qo = qout + (size_t)i * QSLOT + (size_t)(p * 64 + l4 * 4 + ll) * INN;
        qo[t] = a0[ll]; qo[t + 256] = a1[ll];
    }
}

// ---------- K,V projection: f16 single-MFMA, x LDS-staged f16 ----------------
// launch_bounds min-waves stays 2 — accK+accV need 128 VGPRs (r5 lesson).
__global__ __launch_bounds__(512, 2) void kv_kernel(
        const float* __restrict__ x, const unsigned short* __restrict__ WthA,
        const unsigned short* __restrict__ WvhA,
        unsigned short* __restrict__ Kh, unsigned short* __restrict__ Vt, int i0) {
    __shared__ unsigned short xs[64 * 256];   // 32KB: [s][ch] f16, swizzled
    int bx = blockIdx.x & 255, i_local = blockIdx.x >> 8;
    int i = i0 + i_local;
    int b = bx >> 4, sb = bx & 15;
    int t = threadIdx.x, w = t >> 6, lane = t & 63, c = lane & 15, g = lane >> 4;
    int h = w;
    const unsigned short* wth = WthA + (size_t)i * 131072;
    const unsigned short* wvh = WvhA + (size_t)i * 131072;
    unsigned short* Khp = Kh + (size_t)i_local * KSLOT;
    unsigned short* Vtp = Vt + (size_t)i_local * KSLOT;

    // stage x tile: unit = s(64) x ch-quad(64); coalesced 4 loads along s
#pragma unroll
    for (int it = 0; it < 8; ++it) {
        int unit = t + it * 512;
        int s = unit & 63, ch0 = (unit >> 6) * 4;
        const float* xp = x + ((size_t)b * Cc + ch0) * Ss + sb * 64 + s;
        float v0 = xp[0], v1 = xp[Ss], v2 = xp[2 * Ss], v3 = xp[3 * Ss];
        uint2 pk;
        pk.x = f2h(v0) | ((unsigned)f2h(v1) << 16);
        pk.y = f2h(v2) | ((unsigned)f2h(v3) << 16);
        int addr16 = s * 256 + (((ch0 >> 3) ^ (s & 7)) << 3) + (ch0 & 7);
        *(uint2*)(xs + addr16) = pk;
    }
    __syncthreads();

    f32x4 accK[4][4], accV[4][4];          // accK[nt(dh)][st(s)], accV[st][nt]
#pragma unroll
    for (int a = 0; a < 4; ++a)
#pragma unroll
      for (int s = 0; s < 4; ++s) {
        accK[a][s] = (f32x4){0.f, 0.f, 0.f, 0.f};
        accV[a][s] = (f32x4){0.f, 0.f, 0.f, 0.f};
      }

#pragma unroll
    for (int cs = 0; cs < 8; ++cs) {
        f16x8 xf[4];
#pragma unroll
        for (int st = 0; st < 4; ++st) {
            int s = st * 16 + c;
            xf[st] = __builtin_bit_cast(f16x8,
                ((const uint4*)xs)[s * 32 + ((cs * 4 + g) ^ (s & 7))]);
        }
        int c0 = cs * 32 + g * 8;
#pragma unroll
        for (int nt = 0; nt < 4; ++nt) {
            int n = h * 64 + nt * 16 + c;
            f16x8 bk = __builtin_bit_cast(f16x8, *(const uint4*)(wth + (size_t)n * Cc + c0));
            f16x8 bv = __builtin_bit_cast(f16x8, *(const uint4*)(wvh + (size_t)n * Cc + c0));
#pragma unroll
            for (int st = 0; st < 4; ++st) {
                accK[nt][st] = __builtin_amdgcn_mfma_f32_16x16x32_f16(bk, xf[st], accK[nt][st], 0, 0, 0);
                accV[st][nt] = __builtin_amdgcn_mfma_f32_16x16x32_f16(xf[st], bv, accV[st][nt], 0, 0, 0);
            }
        }
    }

#pragma unroll
    for (int nt = 0; nt < 4; ++nt)
#pragma unroll
      for (int st = 0; st < 4; ++st) {
        // K: s = sb*64+st*16+c ; dh = nt*16+g*4+r  (4 consecutive dh -> uint2)
        size_t kb = ((size_t)(b * Hh + h) * Ss + sb * 64 + st * 16 + c) * DHd
                    + nt * 16 + g * 4;
        uint2 ph;
        ph.x = f2h(accK[nt][st][0]) | ((unsigned)f2h(accK[nt][st][1]) << 16);
        ph.y = f2h(accK[nt][st][2]) | ((unsigned)f2h(accK[nt][st][3]) << 16);
        *(uint2*)(Khp + kb) = ph;
        // V^T: dh = nt*16+c ; s = sb*64+st*16+g*4+r
        size_t vb = ((size_t)(b * Hh + h) * DHd + nt * 16 + c) * Ss
                    + sb * 64 + st * 16 + g * 4;
        uint2 pv;
        pv.x = f2h(accV[st][nt][0]) | ((unsigned)f2h(accV[st][nt][1]) << 16);
        pv.y = f2h(accV[st][nt][2]) | ((unsigned)f2h(accV[st][nt][3]) << 16);
        *(uint2*)(Vtp + vb) = pv;
      }
}

// ---------- pass A: f16 scores -> d = sum exp2(s), deferred reduce -----------
__global__ __launch_bounds__(512, 2) void passA_kernel(
        const float* __restrict__ q, const unsigned short* __restrict__ Kh,
        float* __restrict__ md, int i0) {
    __shared__ unsigned short Klds[4096];
    int bx = blockIdx.x & 255, i_local = blockIdx.x >> 8;
    int i = i0 + i_local;
    int b = bx >> 4, h = (bx >> 1) & 7, sh = bx & 1;
    int t = threadIdx.x, p = t >> 6, lane = t & 63, c = lane & 15, g = lane >> 4;
    const float* qb = q + (size_t)i * QSLOT;
    const unsigned short* Khp = Kh + (size_t)i_local * KSLOT;

    f16x8 qf[4][2];
#pragma unroll
    for (int mt = 0; mt < 4; ++mt)
#pragma unroll
      for (int kt = 0; kt < 2; ++kt) {
        const float* qp = qb + (size_t)(p * 64 + mt * 16 + c) * INN + h * 64 + kt * 32 + g * 8;
        f16x8 f;
#pragma unroll
        for (int e = 0; e < 8; ++e) f[e] = (_Float16)(qp[e] * KSC);
        qf[mt][kt] = f;
      }

    float d[4][4];
#pragma unroll
    for (int a = 0; a < 4; ++a)
#pragma unroll
      for (int r = 0; r < 4; ++r) d[a][r] = 0.f;

    int srow = t >> 3, g8 = t & 7, swz = g8 ^ (srow & 7);
    size_t rowb = (size_t)(b * Hh + h) * Ss;
    uint4 rK = *(const uint4*)(Khp + (rowb + sh * 512 + srow) * DHd + g8 * 8);

    for (int ch = 0; ch < 8; ++ch) {
        int sbase = sh * 512 + ch * 64;
        ((uint4*)Klds)[srow * 8 + swz] = rK;
        __syncthreads();
        if (ch < 7)
            rK = *(const uint4*)(Khp + (rowb + sbase + 64 + srow) * DHd + g8 * 8);

        f32x4 acc[4][4];
#pragma unroll
        for (int a = 0; a < 4; ++a)
#pragma unroll
          for (int s = 0; s < 4; ++s) acc[a][s] = (f32x4){0.f, 0.f, 0.f, 0.f};

#pragma unroll
        for (int kt = 0; kt < 2; ++kt)
#pragma unroll
          for (int st = 0; st < 4; ++st) {
            int srw = st * 16 + c;
            f16x8 kf = __builtin_bit_cast(f16x8,
                ((const uint4*)Klds)[srw * 8 + ((kt * 4 + g) ^ (srw & 7))]);
#pragma unroll
            for (int mt = 0; mt < 4; ++mt)
                acc[mt][st] = __builtin_amdgcn_mfma_f32_16x16x32_f16(
                    qf[mt][kt], kf, acc[mt][st], 0, 0, 0);
          }

#pragma unroll
        for (int mt = 0; mt < 4; ++mt)
#pragma unroll
          for (int r = 0; r < 4; ++r)
            d[mt][r] += (__builtin_exp2f(acc[mt][0][r]) + __builtin_exp2f(acc[mt][1][r]))
                      + (__builtin_exp2f(acc[mt][2][r]) + __builtin_exp2f(acc[mt][3][r]));
        __syncthreads();
    }

    float* mdp = md + (size_t)i_local * MDSLOT;
#pragma unroll
    for (int mt = 0; mt < 4; ++mt)
#pragma unroll
      for (int r = 0; r < 4; ++r) {
        float v = d[mt][r];
        v += __shfl_xor(v, 1); v += __shfl_xor(v, 2);
        v += __shfl_xor(v, 4); v += __shfl_xor(v, 8);
        if (c == 0) {
            int row = mt * 16 + g * 4 + r;
            mdp[(((size_t)(b * Hh + h) * 2 + sh) * Pp + p) * Ll + row] = v;
        }
      }
}

// ---------- pass B: f16 scores (C-init = -log2 d) -> probs, heat, PV ---------
__global__ __launch_bounds__(512) void passB_kernel(
        const float* __restrict__ q, const unsigned short* __restrict__ Kh,
        const unsigned short* __restrict__ Vt,
        const float* __restrict__ md, float* __restrict__ heatp,
        unsigned short* __restrict__ outp, int i0) {
    __shared__ unsigned short Khl_[4096];      // 8KB
    __shared__ unsigned short Vtl_[4096];      // 8KB
    __shared__ unsigned short plds[8 * 2048];  // 32KB, per-wave subtiled for tr
    int bx = blockIdx.x & 255, i_local = blockIdx.x >> 8;
    int i = i0 + i_local;
    int b = bx >> 4, h = (bx >> 1) & 7, sh = bx & 1;
    int t = threadIdx.x, p = t >> 6, lane = t & 63, c = lane & 15, g = lane >> 4;
    const float* qb = q + (size_t)i * QSLOT;
    const unsigned short* Khp = Kh + (size_t)i_local * KSLOT;
    const unsigned short* Vtp = Vt + (size_t)i_local * KSLOT;
    const float* mdp = md + (size_t)i_local * MDSLOT;
    float* hpp = heatp + (size_t)i_local * HEATSLOT;
    unsigned short* opp = outp + (size_t)i_local * OUTSLOT;

    f32x4 lgd[4];   // -log2(d) per row -> MFMA C-init folds 1/d into exp2
#pragma unroll
    for (int mt = 0; mt < 4; ++mt)
#pragma unroll
      for (int r = 0; r < 4; ++r) {
        int row = mt * 16 + g * 4 + r;
        size_t j0 = (((size_t)(b * Hh + h) * 2 + 0) * Pp + p) * Ll + row;
        size_t j1 = (((size_t)(b * Hh + h) * 2 + 1) * Pp + p) * Ll + row;
        lgd[mt][r] = -__builtin_log2f(mdp[j0] + mdp[j1]);
      }

    f16x8 qf[4][2];
#pragma unroll
    for (int mt = 0; mt < 4; ++mt)
#pragma unroll
      for (int kt = 0; kt < 2; ++kt) {
        const float* qp = qb + (size_t)(p * 64 + mt * 16 + c) * INN + h * 64 + kt * 32 + g * 8;
        f16x8 f;
#pragma unroll
        for (int e = 0; e < 8; ++e) f[e] = (_Float16)(qp[e] * KSC);
        qf[mt][kt] = f;
      }

    f32x4 o[4][4];
#pragma unroll
    for (int a = 0; a < 4; ++a)
#pragma unroll
      for (int s = 0; s < 4; ++s) o[a][s] = (f32x4){0.f, 0.f, 0.f, 0.f};

    int srow = t >> 3, g8 = t & 7, swz = g8 ^ (srow & 7);
    size_t rowK = (size_t)(b * Hh + h) * Ss;
    size_t rowV = ((size_t)(b * Hh + h) * DHd + srow) * Ss;
    uint4 rK = *(const uint4*)(Khp + (rowK + sh * 512 + srow) * DHd + g8 * 8);
    uint4 rV = *(const uint4*)(Vtp + rowV + sh * 512 + g8 * 8);

    unsigned short* pwb = plds + p * 2048 + ((c >> 2) & 1) * 256 + (c & 3) * 16 + g * 4;
    const unsigned short* trb = plds + p * 2048 + g * 64 + c;

    for (int ch = 0; ch < 8; ++ch) {
        int sbase = sh * 512 + ch * 64;
        int dst = srow * 8 + swz;
        ((uint4*)Khl_)[dst] = rK;
        ((uint4*)Vtl_)[dst] = rV;
        __syncthreads();
        if (ch < 7) {
            rK = *(const uint4*)(Khp + (rowK + sbase + 64 + srow) * DHd + g8 * 8);
            rV = *(const uint4*)(Vtp + rowV + sbase + 64 + g8 * 8);
        }

#pragma unroll
        for (int half = 0; half < 2; ++half) {
            f32x4 sacc[4][2];
#pragma unroll
            for (int a = 0; a < 4; ++a)
#pragma unroll
              for (int s = 0; s < 2; ++s) sacc[a][s] = lgd[a];

#pragma unroll
            for (int kt = 0; kt < 2; ++kt)
#pragma unroll
              for (int s2 = 0; s2 < 2; ++s2) {
                int srw = (half * 2 + s2) * 16 + c;
                f16x8 kf = __builtin_bit_cast(f16x8,
                    ((const uint4*)Khl_)[srw * 8 + ((kt * 4 + g) ^ (srw & 7))]);
#pragma unroll
                for (int mt = 0; mt < 4; ++mt)
                    sacc[mt][s2] = __builtin_amdgcn_mfma_f32_16x16x32_f16(
                        qf[mt][kt], kf, sacc[mt][s2], 0, 0, 0);
              }

            // probs (already normalized via C-init) -> packed plds + heat
#pragma unroll
            for (int s2 = 0; s2 < 2; ++s2) {
                float hs = 0.f;
#pragma unroll
                for (int mt = 0; mt < 4; ++mt) {
                    float pv0 = __builtin_exp2f(sacc[mt][s2][0]);
                    float pv1 = __builtin_exp2f(sacc[mt][s2][1]);
                    float pv2 = __builtin_exp2f(sacc[mt][s2][2]);
                    float pv3 = __builtin_exp2f(sacc[mt][s2][3]);
                    hs += (pv0 + pv1) + (pv2 + pv3);
                    uint2 pk;
                    pk.x = __builtin_bit_cast(unsigned, __builtin_amdgcn_cvt_pkrtz(pv0, pv1));
                    pk.y = __builtin_bit_cast(unsigned, __builtin_amdgcn_cvt_pkrtz(pv2, pv3));
                    *(uint2*)(pwb + mt * 512 + (s2 * 2 + (c >> 3)) * 64) = pk;
                }
                hs += __shfl_xor(hs, 16);
                hs += __shfl_xor(hs, 32);
                if (g == 0) {
                    int sgl = sbase + (half * 2 + s2) * 16 + c;
                    hpp[((size_t)(b * Pp + p) * Ss + sgl) * Hh + h] = hs;
                }
            }

            // PV via hardware transpose reads
            f16x8 vbf[4];
#pragma unroll
            for (int dht = 0; dht < 4; ++dht) {
                int row = dht * 16 + c;
                vbf[dht] = __builtin_bit_cast(f16x8,
                    ((const uint4*)Vtl_)[row * 8 + ((half * 4 + g) ^ (c & 7))]);
            }
            u32x2 ta[4][2];
#pragma unroll
            for (int mt = 0; mt < 4; ++mt) {
                ta[mt][0] = ds_tr16(trb + mt * 512);
                ta[mt][1] = ds_tr16(trb + mt * 512 + 256);
            }
            asm volatile("s_waitcnt lgkmcnt(0)" ::: "memory");
            __builtin_amdgcn_sched_barrier(0);
#pragma unroll
            for (int mt = 0; mt < 4; ++mt) {
                f16x8 pa = __builtin_bit_cast(f16x8,
                    (u32x4){ta[mt][0][0], ta[mt][0][1], ta[mt][1][0], ta[mt][1][1]});
#pragma unroll
                for (int dht = 0; dht < 4; ++dht)
                    o[mt][dht] = __builtin_amdgcn_mfma_f32_16x16x32_f16(
                        pa, vbf[dht], o[mt][dht], 0, 0, 0);
            }
        }
        __syncthreads();
    }

#pragma unroll
    for (int mt = 0; mt < 4; ++mt)
#pragma unroll
      for (int dht = 0; dht < 4; ++dht)
#pragma unroll
        for (int r = 0; r < 4; ++r) {
            int row = mt * 16 + g * 4 + r;
            opp[(((((size_t)sh * Bq + b) * Hh + h) * Pp + p) * Ll + row) * DHd
                + dht * 16 + c] = f2bf(o[mt][dht][r]);
        }
}

// ---------- finalize: deterministic argmax + dist ----------------------------
__global__ __launch_bounds__(256) void fin_kernel(
        const float* __restrict__ heatp, const unsigned short* __restrict__ outp,
        const float* __restrict__ q, float* __restrict__ out, int i0) {
    __shared__ float rv[4];
    __shared__ int   ri[4];
    __shared__ float rs[4];
    int bx = blockIdx.x & 127, i_local = blockIdx.x >> 7;
    int i = i0 + i_local;
    int b = bx >> 3, p = bx & 7;
    int t = threadIdx.x, w = t >> 6, lane = t & 63;
    const float* qb = q + (size_t)i * QSLOT;
    const float* hp = heatp + (size_t)i_local * HEATSLOT;
    const unsigned short* ob = outp + (size_t)i_local * OUTSLOT;

    float best = -1e30f; int bidx = 0;
#pragma unroll
    for (int it = 0; it < 4; ++it) {
        int s = t + it * 256;
        const float* hv8 = hp + ((size_t)(b * Pp + p) * Ss + s) * Hh;
        float4 h0 = *(const float4*)hv8;
        float4 h1 = *(const float4*)(hv8 + 4);
        float hv = ((h0.x + h0.y) + (h0.z + h0.w)) + ((h1.x + h1.y) + (h1.z + h1.w));
        if (hv > best) { best = hv; bidx = s; }
    }
#pragma unroll
    for (int off = 1; off < 64; off <<= 1) {
        float vo = __shfl_xor(best, off);
        int   io = __shfl_xor(bidx, off);
        if (vo > best || (vo == best && io < bidx)) { best = vo; bidx = io; }
    }
    if (lane == 0) { rv[w] = best; ri[w] = bidx; }
    __syncthreads();
    if (t == 0) {
#pragma unroll
        for (int u = 1; u < 4; ++u)
            if (rv[u] > best || (rv[u] == best && ri[u] < bidx)) { best = rv[u]; bidx = ri[u]; }
        out[384 + b * 24 + i * Pp + p] = (float)bidx;
    }

    float sum = 0.f;
#pragma unroll 4
    for (int it = 0; it < 32; ++it) {
        int idx2 = t + it * 256;
        int dh4 = idx2 & 15, l = (idx2 >> 4) & 63, hh = idx2 >> 10;
        size_t base = ((size_t)((b * Hh + hh) * Pp + p) * 4096) + l * 64 + dh4 * 4;
        uint2 o0 = *(const uint2*)(ob + base);
        uint2 o1 = *(const uint2*)(ob + HALFO + base);
        float4 qv = *(const float4*)(qb + (size_t)(p * 64 + l) * INN + hh * 64 + dh4 * 4);
        float d0 = qv.x - (bf2f(o0.x & 0xFFFF) + bf2f(o1.x & 0xFFFF));
        float d1 = qv.y - (bf2f(o0.x >> 16)    + bf2f(o1.x >> 16));
        float d2 = qv.z - (bf2f(o0.y & 0xFFFF) + bf2f(o1.y & 0xFFFF));
        float d3 = qv.w - (bf2f(o0.y >> 16)    + bf2f(o1.y >> 16));
        sum += (d0 * d0 + d1 * d1) + (d2 * d2 + d3 * d3);
    }
#pragma unroll
    for (int off = 32; off; off >>= 1) sum += __shfl_down(sum, off);
    if (lane == 0) rs[w] = sum;
    __syncthreads();
    if (t == 0)
        out[b * 24 + i * Pp + p] = (rs[0] + rs[1] + rs[2] + rs[3]) / (float)(Ll * INN);
}

extern "C" void kernel_launch(void* const* d_in, const int* in_sizes, int n_in,
                              void* d_out, int out_size, void* d_ws, size_t ws_size,
                              hipStream_t stream) {
    const float* x    = (const float*)d_in[0];
    const float* prot = (const float*)d_in[1];
    const float* Wq   = (const float*)d_in[2];
    const float* Wk   = (const float*)d_in[3];
    const float* Wv   = (const float*)d_in[4];
    float* out = (float*)d_out;
    float* ws  = (float*)d_ws;

    // batched (3-slot) layout needs ~173 MB; fallback (1-slot) ~63 MB
    const size_t needB = 173100000ull;
    bool batched = ws_size >= needB;
    size_t NS = batched ? 3 : 1;

    float* qbuf  = ws;                                   // 3*QSLOT f32 (always)
    float* md    = qbuf + 3 * QSLOT;                     // NS*MDSLOT
    float* heatp = md + NS * MDSLOT;                     // NS*HEATSLOT
    unsigned short* outp = (unsigned short*)(heatp + NS * HEATSLOT); // NS*OUTSLOT
    unsigned short* Kh  = outp + NS * OUTSLOT;           // NS*KSLOT (f16)
    unsigned short* Vt  = Kh + NS * KSLOT;               // NS*KSLOT (f16)
    unsigned short* Wth = Vt + NS * KSLOT;               // 3*WSLOT (f16)
    unsigned short* Wvh = Wth + 3 * WSLOT;

    wsplit_kernel<<<192, 256, 0, stream>>>(Wk, Wv, Wth, Wvh);
    qk_kernel    <<<384, 256, 0, stream>>>(prot, Wq, qbuf);
    if (batched) {
        kv_kernel   <<<768, 512, 0, stream>>>(x, Wth, Wvh, Kh, Vt, 0);
        passA_kernel<<<768, 512, 0, stream>>>(qbuf, Kh, md, 0);
        passB_kernel<<<768, 512, 0, stream>>>(qbuf, Kh, Vt, md, heatp, outp, 0);
        fin_kernel  <<<384, 256, 0, stream>>>(heatp, outp, qbuf, out, 0);
    } else {
        for (int i = 0; i < 3; ++i) {
            kv_kernel   <<<256, 512, 0, stream>>>(x, Wth, Wvh, Kh, Vt, i);
            passA_kernel<<<256, 512, 0, stream>>>(qbuf, Kh, md, i);
            passB_kernel<<<256, 512, 0, stream>>>(qbuf, Kh, Vt, md, heatp, outp, i);
            fin_kernel  <<<128, 256, 0, stream>>>(heatp, outp, qbuf, out, i);
        }
    }
}